// Round 1
// 1998.958 us; speedup vs baseline: 1.1681x; 1.1681x over previous
//
#include <hip/hip_runtime.h>
#include <hip/hip_bf16.h>
#include <stdint.h>

// Problem dims (fixed by setup_inputs)
constexpr int T  = 4 * 2048;   // tokens = B*S
constexpr int H  = 1536;
constexpr int I2 = 6144;       // 2 * intermediate
constexpr int II = 3072;       // intermediate
constexpr int EE = 16;         // experts
#define ALPHA_ 1.702f
#define LIMIT_ 7.0f
#define EPS_   1e-6f

typedef unsigned short u16;
typedef __bf16 bf16x8 __attribute__((ext_vector_type(8)));
typedef float  f32x4  __attribute__((ext_vector_type(4)));

__device__ __forceinline__ u16 f2bf(float f) {
  union { float f; unsigned int u; } c; c.f = f;
  unsigned int u = c.u + 0x7fffu + ((c.u >> 16) & 1u);  // RTNE
  return (u16)(u >> 16);
}
__device__ __forceinline__ unsigned int pack2(float lo, float hi) {
  return (unsigned int)f2bf(lo) | ((unsigned int)f2bf(hi) << 16);
}

// async global->LDS, 16B per lane. LDS dest must be wave-uniform base + lane*16.
__device__ __forceinline__ void async16(const void* g, void* l) {
  __builtin_amdgcn_global_load_lds(
      (const __attribute__((address_space(1))) unsigned int*)(uintptr_t)g,
      (__attribute__((address_space(3))) unsigned int*)(unsigned int)(uintptr_t)l,
      16, 0, 0);
}

// ---------------- K1: RMSNorm + router logits ----------------
__global__ __launch_bounds__(256) void k_rms_router(
    const float* __restrict__ x, const float* __restrict__ nscale,
    const float* __restrict__ gw, u16* __restrict__ xnb,
    float* __restrict__ logits) {
  const int t = blockIdx.x;
  const int tid = threadIdx.x;
  const int lane = tid & 63, wid = tid >> 6;
  const float* xr = x + (size_t)t * H;
  float v[6]; float ss = 0.f;
#pragma unroll
  for (int j = 0; j < 6; ++j) { v[j] = xr[tid + j * 256]; ss += v[j] * v[j]; }
  __shared__ float red[4];
  for (int off = 32; off; off >>= 1) ss += __shfl_down(ss, off, 64);
  if (lane == 0) red[wid] = ss;
  __syncthreads();
  const float rs = rsqrtf((red[0] + red[1] + red[2] + red[3]) * (1.0f / H) + EPS_);
  float xn[6];
#pragma unroll
  for (int j = 0; j < 6; ++j) {
    const int i = tid + j * 256;
    xn[j] = v[j] * rs * nscale[i];
    xnb[(size_t)t * H + i] = f2bf(xn[j]);
  }
  float acc[16];
#pragma unroll
  for (int e = 0; e < 16; ++e) acc[e] = 0.f;
#pragma unroll
  for (int j = 0; j < 6; ++j) {
    const int i = tid + j * 256;
#pragma unroll
    for (int e = 0; e < 16; ++e) acc[e] += xn[j] * gw[e * H + i];
  }
  __shared__ float lred[4][16];
#pragma unroll
  for (int e = 0; e < 16; ++e) {
    float a = acc[e];
    for (int off = 32; off; off >>= 1) a += __shfl_down(a, off, 64);
    if (lane == 0) lred[wid][e] = a;
  }
  __syncthreads();
  if (tid < 16)
    logits[(size_t)t * 16 + tid] = lred[0][tid] + lred[1][tid] + lred[2][tid] + lred[3][tid];
}

// ---------------- K2: per-token top-4 + softmax; token-0 expert ids ----------------
__global__ __launch_bounds__(256) void k_topk(
    const float* __restrict__ logits, float* __restrict__ probs, int* __restrict__ eids) {
  const int t = blockIdx.x * 256 + threadIdx.x;
  if (t >= T) return;
  float v[16];
#pragma unroll
  for (int e = 0; e < 16; ++e) v[e] = logits[(size_t)t * 16 + e];
  float tv[4]; int ti[4]; unsigned used = 0;
#pragma unroll
  for (int j = 0; j < 4; ++j) {
    float best = -3.4e38f; int bi = 0;
#pragma unroll
    for (int e = 0; e < 16; ++e) {
      if (!((used >> e) & 1u) && v[e] > best) { best = v[e]; bi = e; }
    }
    used |= 1u << bi; tv[j] = best; ti[j] = bi;
  }
  const float m = tv[0];
  float ex[4], den = 0.f;
#pragma unroll
  for (int j = 0; j < 4; ++j) { ex[j] = __expf(tv[j] - m); den += ex[j]; }
  const float rden = 1.0f / den;
#pragma unroll
  for (int j = 0; j < 4; ++j) probs[(size_t)t * 4 + j] = ex[j] * rden;
  if (t == 0) {
#pragma unroll
    for (int j = 0; j < 4; ++j) eids[j] = ti[j] % EE;
  }
}

// ---------------- K3a: gather biases for the 4 selected experts ----------------
__global__ __launch_bounds__(256) void k_gather_bias(
    const float* __restrict__ bup, const float* __restrict__ bdn,
    const int* __restrict__ eids, float* __restrict__ bu_g, float* __restrict__ bd_g) {
  const int i = blockIdx.x * 256 + threadIdx.x;   // grid sized exactly 4*I2+4*H
  if (i < 4 * I2) {
    const int s = i / I2, r = i - s * I2;
    bu_g[i] = bup[(size_t)eids[s] * I2 + r];
  } else {
    const int j = i - 4 * I2;
    const int s = j / H, r = j - s * H;
    bd_g[j] = bdn[(size_t)eids[s] * H + r];
  }
}

// ---------------- K3b: gather + fp32->bf16 convert selected expert weights ----------------
__global__ __launch_bounds__(256) void k_gather_w(
    const float* __restrict__ wup, const float* __restrict__ wdn,
    const int* __restrict__ eids, u16* __restrict__ wu_b, u16* __restrict__ wd_b) {
  const size_t UP = (size_t)4 * I2 * H;
  const size_t u = ((size_t)blockIdx.x * 256 + threadIdx.x) * 8;  // grid sized exactly
  if (u < UP) {
    const int s = (int)(u / ((size_t)I2 * H));
    const size_t r = u - (size_t)s * I2 * H;
    const float4* src = (const float4*)(wup + (size_t)eids[s] * I2 * H + r);
    const float4 a = src[0], b = src[1];
    uint4 o; o.x = pack2(a.x, a.y); o.y = pack2(a.z, a.w);
    o.z = pack2(b.x, b.y); o.w = pack2(b.z, b.w);
    *(uint4*)(wu_b + u) = o;
  } else {
    const size_t q = u - UP;
    const int s = (int)(q / ((size_t)H * II));
    const size_t r = q - (size_t)s * H * II;
    const float4* src = (const float4*)(wdn + (size_t)eids[s] * H * II + r);
    const float4 a = src[0], b = src[1];
    uint4 o; o.x = pack2(a.x, a.y); o.y = pack2(a.z, a.w);
    o.z = pack2(b.x, b.y); o.w = pack2(b.z, b.w);
    *(uint4*)(wd_b + q) = o;
  }
}

// ============================================================================
// 8-phase 256-class GEMM template (per cdna_hip_programming.md §5):
//  - rows are 128 B (BK=64 bf16); LDS XOR-swizzle byte^=(row&7)<<4 applied on
//    ds_read addr and INVERTED on the global_load_lds source (both-sides rule)
//  - raw s_barrier (no vmcnt(0) drain), counted vmcnt (6 / 4), setprio around MFMA
//  - stage exactly one 16KB half-tile (2 async16/thread) per phase
//  - wave M-rows interleaved (mi*128 + wm*64) so phase mi touches only A-half mi:
//    every LDS overwrite is >=1 barrier after the last read of the old content
// ============================================================================

// logical (row, kq-byte) -> swizzled LDS read
#define FRAG16(base, row, kq) \
  (*(const bf16x8*)((const char*)(base) + ((row) * 128 + ((kq) ^ (((row) & 7) << 4)))))

constexpr int NT1 = H / 64;   // 24 K-tiles for gemm1

// ---------------- K4: GEMM1 (xn @ w_up^T) + bias + SwiGLU + prob scale ----------------
// BM=256 tokens, dual-B 128 g-cols + 128 l-cols. 8 waves = 2(M) x 4(N).
// LDS: 2 bufs x [A 32K | A1 at +16384 | Bg +32768 | Bl +49152] = 128 KiB.
// K-tile parts (stage order): 0=A-lo, 1=Bg, 2=Bl, 3=A-hi.
// Phases: p0 A-lo+Bg->accg[0..3] | p1 Bl->accl[0..3] | p2 A-hi->accg[4..7] | p3 ->accl[4..7]
__global__ __launch_bounds__(512, 2) void k_gemm1(
    const u16* __restrict__ xnb, const u16* __restrict__ wu_b,
    const float* __restrict__ bu_g, const float* __restrict__ probs,
    u16* __restrict__ act) {
  extern __shared__ float4 smem_f4[];
  char* smem = (char*)smem_f4;
  const int s = blockIdx.z;
  int wg = blockIdx.x + 24 * blockIdx.y;          // 768 per slot, 768%8==0
  wg = (wg & 7) * 96 + (wg >> 3);                 // bijective XCD swizzle
  const int n0 = (wg % 24) * 128;                 // g-col tile in [0, II)
  const int m0 = (wg / 24) * 256;                 // token tile
  const int tid = threadIdx.x;
  const int lane = tid & 63, wid = tid >> 6;
  const int wm = wid >> 2, wn = wid & 3;
  const int r16 = lane & 15, q16 = (lane >> 4) * 16;
  const u16* wug = wu_b + (size_t)s * I2 * H;

  auto stage = [&](int k, int part) {             // part is literal at call sites
    char* base = smem + (k & 1) * 65536;
    const u16* g; char* dst;
    if (part == 0)      { g = xnb + (size_t) m0        * H + k * 64; dst = base;          }
    else if (part == 1) { g = wug + (size_t) n0        * H + k * 64; dst = base + 32768; }
    else if (part == 2) { g = wug + (size_t)(II + n0)  * H + k * 64; dst = base + 49152; }
    else                { g = xnb + (size_t)(m0 + 128) * H + k * 64; dst = base + 16384; }
#pragma unroll
    for (int c = 0; c < 2; ++c) {
      const int o = c * 8192 + tid * 16;          // linear LDS dest (HW requirement)
      const int row = o >> 7;
      const int cb = (o & 127) ^ ((row & 7) << 4);  // inverse-swizzled global col
      async16(g + (size_t)row * H + (cb >> 1), dst + o);
    }
  };

  f32x4 accg[8][2], accl[8][2];
  const f32x4 z = {0.f, 0.f, 0.f, 0.f};
#pragma unroll
  for (int i = 0; i < 8; ++i)
#pragma unroll
    for (int j = 0; j < 2; ++j) { accg[i][j] = z; accl[i][j] = z; }

  // prologue: K-tile 0 fully + 3 parts of K-tile 1 (7 half-tiles = 14 loads)
  stage(0, 0); stage(0, 1); stage(0, 2); stage(0, 3);
  stage(1, 0); stage(1, 1); stage(1, 2);
  asm volatile("s_waitcnt vmcnt(6)" ::: "memory");   // K-tile 0 landed
  __builtin_amdgcn_s_barrier();

  bf16x8 a[4][2], bg[2][2], bl[2][2];
#pragma unroll 1
  for (int t = 0; t < NT1; ++t) {
    const char* base = smem + (t & 1) * 65536;
    const u16* A  = (const u16*)base;
    const u16* Bg = (const u16*)(base + 32768);
    const u16* Bl = (const u16*)(base + 49152);
    const bool lastt = (t == NT1 - 1);

    // ---- phase 0: A-lo + Bg -> accg[0..3]
#pragma unroll
    for (int i = 0; i < 4; ++i)
#pragma unroll
      for (int k = 0; k < 2; ++k)
        a[i][k] = FRAG16(A, wm * 64 + i * 16 + r16, k * 64 + q16);
#pragma unroll
    for (int j = 0; j < 2; ++j)
#pragma unroll
      for (int k = 0; k < 2; ++k)
        bg[j][k] = FRAG16(Bg, wn * 32 + j * 16 + r16, k * 64 + q16);
    if (t + 1 < NT1) stage(t + 1, 3);
    __builtin_amdgcn_s_barrier();
    asm volatile("s_waitcnt lgkmcnt(0)" ::: "memory");
    __builtin_amdgcn_s_setprio(1);
#pragma unroll
    for (int i = 0; i < 4; ++i)
#pragma unroll
      for (int j = 0; j < 2; ++j) {
        accg[i][j] = __builtin_amdgcn_mfma_f32_16x16x32_bf16(a[i][0], bg[j][0], accg[i][j], 0, 0, 0);
        accg[i][j] = __builtin_amdgcn_mfma_f32_16x16x32_bf16(a[i][1], bg[j][1], accg[i][j], 0, 0, 0);
      }
    __builtin_amdgcn_s_setprio(0);
    if (lastt) asm volatile("s_waitcnt vmcnt(2)" ::: "memory");  // tail drain
    __builtin_amdgcn_s_barrier();

    // ---- phase 1: Bl -> accl[0..3]
#pragma unroll
    for (int j = 0; j < 2; ++j)
#pragma unroll
      for (int k = 0; k < 2; ++k)
        bl[j][k] = FRAG16(Bl, wn * 32 + j * 16 + r16, k * 64 + q16);
    if (t + 2 < NT1) stage(t + 2, 0);
    __builtin_amdgcn_s_barrier();
    asm volatile("s_waitcnt lgkmcnt(0)" ::: "memory");
    __builtin_amdgcn_s_setprio(1);
#pragma unroll
    for (int i = 0; i < 4; ++i)
#pragma unroll
      for (int j = 0; j < 2; ++j) {
        accl[i][j] = __builtin_amdgcn_mfma_f32_16x16x32_bf16(a[i][0], bl[j][0], accl[i][j], 0, 0, 0);
        accl[i][j] = __builtin_amdgcn_mfma_f32_16x16x32_bf16(a[i][1], bl[j][1], accl[i][j], 0, 0, 0);
      }
    __builtin_amdgcn_s_setprio(0);
    if (lastt) asm volatile("s_waitcnt vmcnt(0)" ::: "memory");  // tail drain
    __builtin_amdgcn_s_barrier();

    // ---- phase 2: A-hi -> accg[4..7]
#pragma unroll
    for (int i = 0; i < 4; ++i)
#pragma unroll
      for (int k = 0; k < 2; ++k)
        a[i][k] = FRAG16(A, 128 + wm * 64 + i * 16 + r16, k * 64 + q16);
    if (t + 2 < NT1) stage(t + 2, 1);
    __builtin_amdgcn_s_barrier();
    asm volatile("s_waitcnt lgkmcnt(0)" ::: "memory");
    __builtin_amdgcn_s_setprio(1);
#pragma unroll
    for (int i = 0; i < 4; ++i)
#pragma unroll
      for (int j = 0; j < 2; ++j) {
        accg[4 + i][j] = __builtin_amdgcn_mfma_f32_16x16x32_bf16(a[i][0], bg[j][0], accg[4 + i][j], 0, 0, 0);
        accg[4 + i][j] = __builtin_amdgcn_mfma_f32_16x16x32_bf16(a[i][1], bg[j][1], accg[4 + i][j], 0, 0, 0);
      }
    __builtin_amdgcn_s_setprio(0);
    __builtin_amdgcn_s_barrier();

    // ---- phase 3: -> accl[4..7] (no new LDS reads)
    if (t + 2 < NT1) stage(t + 2, 2);
    __builtin_amdgcn_s_barrier();
    __builtin_amdgcn_s_setprio(1);
#pragma unroll
    for (int i = 0; i < 4; ++i)
#pragma unroll
      for (int j = 0; j < 2; ++j) {
        accl[4 + i][j] = __builtin_amdgcn_mfma_f32_16x16x32_bf16(a[i][0], bl[j][0], accl[4 + i][j], 0, 0, 0);
        accl[4 + i][j] = __builtin_amdgcn_mfma_f32_16x16x32_bf16(a[i][1], bl[j][1], accl[4 + i][j], 0, 0, 0);
      }
    __builtin_amdgcn_s_setprio(0);
    if (t < NT1 - 2)       asm volatile("s_waitcnt vmcnt(6)" ::: "memory");  // steady: tile t+1 landed
    else if (t == NT1 - 2) asm volatile("s_waitcnt vmcnt(4)" ::: "memory");  // tail entry
    __builtin_amdgcn_s_barrier();
  }

  // epilogue: bias, SwiGLU, per-row prob, store bf16
  u16* actS = act + (size_t)s * T * II;
  const int q4 = (lane >> 4) * 4;
#pragma unroll
  for (int mi = 0; mi < 2; ++mi)
#pragma unroll
    for (int i = 0; i < 4; ++i)
#pragma unroll
      for (int j = 0; j < 2; ++j) {
        const int col = n0 + wn * 32 + j * 16 + r16;
        const float bug = bu_g[s * I2 + col];
        const float bul = bu_g[s * I2 + II + col];
#pragma unroll
        for (int r = 0; r < 4; ++r) {
          const int row = m0 + mi * 128 + wm * 64 + i * 16 + q4 + r;
          float g = accg[mi * 4 + i][j][r] + bug;
          float l = accl[mi * 4 + i][j][r] + bul;
          g = fminf(g, LIMIT_);
          l = fminf(fmaxf(l, -LIMIT_), LIMIT_);
          const float sig = 1.0f / (1.0f + __expf(-ALPHA_ * g));
          const float av = g * sig * (l + 1.0f);
          const float p = probs[(size_t)row * 4 + s];
          actS[(size_t)row * II + col] = f2bf(av * p);
        }
      }
}

// ---------------- K5: GEMM2 over all 4 slots (K=4*II) + residual + bias ----------------
// BM=256, BN=128, 8 waves. LDS: 2 bufs x [A 32K | A1 at +16384 | B +32768] = 96 KiB.
// K-tile parts: 0=A-lo, 1=B, 2=A-hi. Phases: p0 A-lo+B->acc[0..3] | p1 A-hi->acc[4..7].
constexpr int NT2 = 4 * II / 64;  // 192 K-tiles
constexpr int KTS = II / 64;      // 48 per slot

__global__ __launch_bounds__(512, 2) void k_gemm2(
    const u16* __restrict__ act, const u16* __restrict__ wd_b,
    const float* __restrict__ bd_g, const float* __restrict__ probs,
    const float* __restrict__ x, float* __restrict__ out) {
  extern __shared__ float4 smem_f4[];
  char* smem = (char*)smem_f4;
  int wg = blockIdx.x + 12 * blockIdx.y;          // 384 blocks, 384%8==0
  wg = (wg & 7) * 48 + (wg >> 3);                 // bijective XCD swizzle
  const int n0 = (wg % 12) * 128;                 // H tile
  const int m0 = (wg / 12) * 256;                 // token tile
  const int tid = threadIdx.x;
  const int lane = tid & 63, wid = tid >> 6;
  const int wm = wid >> 2, wn = wid & 3;
  const int r16 = lane & 15, q16 = (lane >> 4) * 16;

  auto stage = [&](int t, int part) {
    const int sl = t / KTS, kk = t - sl * KTS;
    char* base = smem + (t & 1) * 49152;
    const u16* g; char* dst;
    if (part == 0)      { g = act  + (size_t)sl * T * II + (size_t) m0        * II + kk * 64; dst = base;          }
    else if (part == 1) { g = wd_b + (size_t)sl * H * II + (size_t) n0        * II + kk * 64; dst = base + 32768; }
    else                { g = act  + (size_t)sl * T * II + (size_t)(m0 + 128) * II + kk * 64; dst = base + 16384; }
#pragma unroll
    for (int c = 0; c < 2; ++c) {
      const int o = c * 8192 + tid * 16;
      const int row = o >> 7;
      const int cb = (o & 127) ^ ((row & 7) << 4);
      async16(g + (size_t)row * II + (cb >> 1), dst + o);
    }
  };

  f32x4 acc[8][2];
  const f32x4 z = {0.f, 0.f, 0.f, 0.f};
#pragma unroll
  for (int i = 0; i < 8; ++i)
#pragma unroll
    for (int j = 0; j < 2; ++j) acc[i][j] = z;

  // prologue: tile 0 fully + 2 parts of tile 1 (5 half-tiles = 10 loads)
  stage(0, 0); stage(0, 1); stage(0, 2); stage(1, 0); stage(1, 1);
  asm volatile("s_waitcnt vmcnt(4)" ::: "memory");   // tile 0 landed
  __builtin_amdgcn_s_barrier();

  bf16x8 a[4][2], b[2][2];
#pragma unroll 1
  for (int t = 0; t < NT2; ++t) {
    const char* base = smem + (t & 1) * 49152;
    const u16* A = (const u16*)base;
    const u16* B = (const u16*)(base + 32768);
    const bool lastt = (t == NT2 - 1);

    // ---- phase 0: A-lo + B -> acc[0..3]
#pragma unroll
    for (int i = 0; i < 4; ++i)
#pragma unroll
      for (int k = 0; k < 2; ++k)
        a[i][k] = FRAG16(A, wm * 64 + i * 16 + r16, k * 64 + q16);
#pragma unroll
    for (int j = 0; j < 2; ++j)
#pragma unroll
      for (int k = 0; k < 2; ++k)
        b[j][k] = FRAG16(B, wn * 32 + j * 16 + r16, k * 64 + q16);
    if (t + 1 < NT2) stage(t + 1, 2);
    __builtin_amdgcn_s_barrier();
    asm volatile("s_waitcnt lgkmcnt(0)" ::: "memory");
    __builtin_amdgcn_s_setprio(1);
#pragma unroll
    for (int i = 0; i < 4; ++i)
#pragma unroll
      for (int j = 0; j < 2; ++j) {
        acc[i][j] = __builtin_amdgcn_mfma_f32_16x16x32_bf16(a[i][0], b[j][0], acc[i][j], 0, 0, 0);
        acc[i][j] = __builtin_amdgcn_mfma_f32_16x16x32_bf16(a[i][1], b[j][1], acc[i][j], 0, 0, 0);
      }
    __builtin_amdgcn_s_setprio(0);
    if (lastt) asm volatile("s_waitcnt vmcnt(0)" ::: "memory");  // tail drain
    __builtin_amdgcn_s_barrier();

    // ---- phase 1: A-hi -> acc[4..7]
#pragma unroll
    for (int i = 0; i < 4; ++i)
#pragma unroll
      for (int k = 0; k < 2; ++k)
        a[i][k] = FRAG16(A, 128 + wm * 64 + i * 16 + r16, k * 64 + q16);
    if (t + 2 < NT2) { stage(t + 2, 0); stage(t + 2, 1); }
    __builtin_amdgcn_s_barrier();
    asm volatile("s_waitcnt lgkmcnt(0)" ::: "memory");
    __builtin_amdgcn_s_setprio(1);
#pragma unroll
    for (int i = 0; i < 4; ++i)
#pragma unroll
      for (int j = 0; j < 2; ++j) {
        acc[4 + i][j] = __builtin_amdgcn_mfma_f32_16x16x32_bf16(a[i][0], b[j][0], acc[4 + i][j], 0, 0, 0);
        acc[4 + i][j] = __builtin_amdgcn_mfma_f32_16x16x32_bf16(a[i][1], b[j][1], acc[4 + i][j], 0, 0, 0);
      }
    __builtin_amdgcn_s_setprio(0);
    if (t < NT2 - 2)       asm volatile("s_waitcnt vmcnt(4)" ::: "memory");  // steady: tile t+1 landed
    else if (t == NT2 - 2) asm volatile("s_waitcnt vmcnt(2)" ::: "memory");  // tail entry
    __builtin_amdgcn_s_barrier();
  }

  const int q4 = (lane >> 4) * 4;
#pragma unroll
  for (int mi = 0; mi < 2; ++mi)
#pragma unroll
    for (int i = 0; i < 4; ++i)
#pragma unroll
      for (int r = 0; r < 4; ++r) {
        const int row = m0 + mi * 128 + wm * 64 + i * 16 + q4 + r;
        const float p0 = probs[(size_t)row * 4 + 0], p1 = probs[(size_t)row * 4 + 1];
        const float p2 = probs[(size_t)row * 4 + 2], p3 = probs[(size_t)row * 4 + 3];
#pragma unroll
        for (int j = 0; j < 2; ++j) {
          const int col = n0 + wn * 32 + j * 16 + r16;
          const float bias = p0 * bd_g[col] + p1 * bd_g[H + col] +
                             p2 * bd_g[2 * H + col] + p3 * bd_g[3 * H + col];
          out[(size_t)row * H + col] = x[(size_t)row * H + col] + acc[mi * 4 + i][j][r] + bias;
        }
      }
}

extern "C" void kernel_launch(void* const* d_in, const int* in_sizes, int n_in,
                              void* d_out, int out_size, void* d_ws, size_t ws_size,
                              hipStream_t stream) {
  const float* x      = (const float*)d_in[0];
  const float* nscale = (const float*)d_in[1];
  const float* gw     = (const float*)d_in[2];
  const float* wup    = (const float*)d_in[3];
  const float* bup    = (const float*)d_in[4];
  const float* wdn    = (const float*)d_in[5];
  const float* bdn    = (const float*)d_in[6];
  float* out = (float*)d_out;
  char* ws = (char*)d_ws;
  size_t off = 0;
  auto alloc = [&](size_t bytes) { size_t o = off; off += (bytes + 255) & ~(size_t)255; return o; };
  u16*   xnb    = (u16*)(ws + alloc((size_t)T * H * 2));       // 25.2 MB
  float* logits = (float*)(ws + alloc((size_t)T * 16 * 4));    // 0.5 MB
  float* probs  = (float*)(ws + alloc((size_t)T * 4 * 4));     // 0.13 MB
  int*   eids   = (int*)(ws + alloc(64));
  float* bu_g   = (float*)(ws + alloc((size_t)4 * I2 * 4));
  float* bd_g   = (float*)(ws + alloc((size_t)4 * H * 4));
  u16*   wu_b   = (u16*)(ws + alloc((size_t)4 * I2 * H * 2));  // 75.5 MB
  u16*   wd_b   = (u16*)(ws + alloc((size_t)4 * H * II * 2));  // 37.7 MB
  u16*   act    = (u16*)(ws + alloc((size_t)4 * T * II * 2));  // 201 MB
  (void)ws_size; (void)in_sizes; (void)n_in; (void)out_size;   // total ~340.5 MB

  // >64KB dynamic LDS opt-in (once per process; host-side, graph-capture safe)
  static bool attr_done = false;
  if (!attr_done) {
    (void)hipFuncSetAttribute((const void*)k_gemm1,
                              hipFuncAttributeMaxDynamicSharedMemorySize, 131072);
    (void)hipFuncSetAttribute((const void*)k_gemm2,
                              hipFuncAttributeMaxDynamicSharedMemorySize, 98304);
    attr_done = true;
  }

  k_rms_router<<<T, 256, 0, stream>>>(x, nscale, gw, xnb, logits);
  k_topk<<<T / 256, 256, 0, stream>>>(logits, probs, eids);
  k_gather_bias<<<(4 * I2 + 4 * H) / 256, 256, 0, stream>>>(bup, bdn, eids, bu_g, bd_g);
  {
    const size_t total = (size_t)4 * I2 * H + (size_t)4 * H * II;
    k_gather_w<<<(unsigned)(total / 8 / 256), 256, 0, stream>>>(wup, wdn, eids, wu_b, wd_b);
  }
  k_gemm1<<<dim3(24, 32, 4), 512, 131072, stream>>>(xnb, wu_b, bu_g, probs, act);
  k_gemm2<<<dim3(12, 32), 512, 98304, stream>>>(act, wd_b, bd_g, probs, x, out);
}